// Round 11
// baseline (43.057 us; speedup 1.0000x reference)
//
#include <hip/hip_runtime.h>

// GaussianAntecedent: out[n,r] = mem[n,r] / (sum_r mem[n,r] + 1e-8)
// mem = exp2( sum_d max( negqq_rd * (x_nd - c_rd)^2 , L ) )
//   negqq = -0.5*log2(e)/(sigma+eps)^2 ,  L = log2(1e-8) < 0
//
// R10 post-mortem: lane=rule layout is the ceiling (~35us): X must be
// broadcast to 64 lanes row-by-row through a contended resource (K$ /
// L1-broadcast / LDS pipe) and each row ends in a serial reduce chain.
// R11 structural flip -- lane = ROW, loop over rules:
//  - lane holds its own x[32] in VGPRs (loaded once per wave, pinned)
//  - rule constants are wave-uniform -> s_load from 16KB table (scalar
//    pipe, K$-resident, <=1 SGPR operand per packed VALU op)
//  - NO cross-lane reduction: sum over rules is a per-lane register acc
//  - mem[64] spilled to per-wave LDS tile [row][rule] (pad 66, 2-way
//    free); 16-step transpose phase -> fully coalesced float4 stores
// Only 1563 waves (occupancy counter will read ~5% -- by design; the
// wave is a ~6us pure-VALU stream with nothing to wait on).

typedef float v2f __attribute__((ext_vector_type(2)));

constexpr int DDIM  = 32;
constexpr int RR    = 64;
constexpr int WPB   = 2;               // waves per block (128 threads)
constexpr int PAD   = 66;              // LDS pitch (floats): 2-way max conflict
constexpr int WSLOT = RR * PAD + RR;   // per-wave LDS floats (mem tile + rS)

__device__ inline float fast_exp2(float x) {
#if __has_builtin(__builtin_amdgcn_exp2f)
    return __builtin_amdgcn_exp2f(x);
#else
    return exp2f(x);
#endif
}

// ---- setup: per-rule table [ c[0..31] | negqq[0..31] ] (64 floats/rule) ----
__global__ void gauss_setup_kernel(const float* __restrict__ centers,
                                   const float* __restrict__ sigma,
                                   float* __restrict__ ws) {
    const float KQ = 0.72134752044448170f;   // 0.5 * log2(e)
    int idx = blockIdx.x * blockDim.x + threadIdx.x;
    if (idx < RR * 64) {
        int r = idx >> 6, k = idx & 63;
        if (k < DDIM) {
            ws[idx] = centers[r * DDIM + k];
        } else {
            float s = sigma[r * DDIM + (k - DDIM)] + 1e-8f;
            ws[idx] = -KQ / (s * s);
        }
    }
}

__global__ __launch_bounds__(128) void gauss_main(
    const float* __restrict__ X,
    const float* __restrict__ tab,    // d_ws table, 64 rules x 64 floats
    float* __restrict__ out, int N)
{
    __shared__ float lds[WPB * WSLOT];   // 2 x 17KB = 34KB
    const int lane = threadIdx.x & 63;
    const int wv   = threadIdx.x >> 6;
    const int wave_id = blockIdx.x * WPB + wv;
    const int n0 = wave_id * 64;
    if (n0 >= N) return;

    float* mlds = &lds[wv * WSLOT];      // [64 rows][PAD] mem tile
    float* slds = mlds + RR * PAD;       // [64] rcp(S)

    // ---- this lane's row -> VGPRs (held for the whole wave) ----
    const int n  = n0 + lane;
    const int nn = (n < N) ? n : (N - 1);   // clamp; store is predicated
    const float4* __restrict__ xr =
        reinterpret_cast<const float4*>(X + (size_t)nn * DDIM);
    v2f x2[16];
    #pragma unroll
    for (int j = 0; j < 8; ++j) {
        float4 v = xr[j];
        x2[2 * j]     = (v2f){v.x, v.y};
        x2[2 * j + 1] = (v2f){v.z, v.w};
    }
    #pragma unroll
    for (int j = 0; j < 16; ++j) asm volatile("" : "+v"(x2[j]));

    const float LC = -26.575424759098897f;   // log2(1e-8)
    const v2f L2 = {LC, LC};
    float S = 0.f;

    // ---- rule loop: constants via scalar path, pure packed VALU ----
    for (int r = 0; r < RR; ++r) {
        const v2f* __restrict__ cr =
            reinterpret_cast<const v2f*>(tab + r * 64);       // c pairs
        const v2f* __restrict__ qr = cr + DDIM / 2;           // negqq pairs

        v2f acc[4] = {{0.f,0.f},{0.f,0.f},{0.f,0.f},{0.f,0.f}};
        #pragma unroll
        for (int p = 0; p < 16; ++p) {
            v2f z  = x2[p] - cr[p];                              // 1 SGPR-pair
            v2f zz = z * z;
            v2f u  = __builtin_elementwise_fma(zz, qr[p], acc[p & 3]); // 1 SGPR-pair
            v2f cl = acc[p & 3] + L2;
            acc[p & 3] = __builtin_elementwise_max(u, cl);       // acc += max(nq*z^2, L)
        }
        v2f a = (acc[0] + acc[1]) + (acc[2] + acc[3]);
        float mem = fast_exp2(a.x + a.y);
        S += mem;
        mlds[lane * PAD + r] = mem;       // bank (2*lane + r)%32: 2-way, free
    }
    slds[lane] = __builtin_amdgcn_rcpf(S + 1e-8f);

    // same-wave produce/consume: lockstep + compiler lgkmcnt waits; no barrier.

    // ---- transpose phase: coalesced float4 stores ----
    #pragma unroll
    for (int t = 0; t < 16; ++t) {
        const int i  = t * 4 + (lane >> 4);     // row within wave tile
        const int r4 = (lane & 15) * 4;         // rule quad
        float2 m0 = *reinterpret_cast<const float2*>(&mlds[i * PAD + r4]);
        float2 m1 = *reinterpret_cast<const float2*>(&mlds[i * PAD + r4 + 2]);
        float rs  = slds[i];                    // broadcast read
        float4 o;
        o.x = m0.x * rs; o.y = m0.y * rs; o.z = m1.x * rs; o.w = m1.y * rs;
        const int row = n0 + i;
        if (row < N) {
            *reinterpret_cast<float4*>(&out[(size_t)row * RR + r4]) = o;
        }
    }
}

extern "C" void kernel_launch(void* const* d_in, const int* in_sizes, int n_in,
                              void* d_out, int out_size, void* d_ws, size_t ws_size,
                              hipStream_t stream) {
    const float* X       = (const float*)d_in[0];
    const float* centers = (const float*)d_in[1];
    const float* sigma   = (const float*)d_in[2];
    float* out = (float*)d_out;
    float* ws  = (float*)d_ws;   // needs 64*64*4 = 16 KB

    const int N = in_sizes[0] / DDIM;  // 100000

    // 1) build the per-rule constant table (4096 floats)
    gauss_setup_kernel<<<(RR * 64 + 255) / 256, 256, 0, stream>>>(
        centers, sigma, ws);

    // 2) main: 1563 waves (64 rows each), 2 waves per block
    const int nwaves = (N + 63) / 64;
    const int grid = (nwaves + WPB - 1) / WPB;
    gauss_main<<<grid, 128, 0, stream>>>(X, ws, out, N);
}

// Round 12
// 35.032 us; speedup vs baseline: 1.2291x; 1.2291x over previous
//
#include <hip/hip_runtime.h>

// GaussianAntecedent: out[n,r] = mem[n,r] / (sum_r mem[n,r] + 1e-8)
// mem = exp2( sum_d max( -(q*x + pn)^2 , L ) ),
//   q = sqrt(0.5*log2 e)/(sigma+eps), pn = -c*q, L = log2(1e-8) < 0
//
// R11 post-mortem: rolled rule-loop + unprefetched uniform loads at 1.5
// waves/SIMD = serial constant-fetch latency. Every round's basin (~35us)
// is one exposed transport. R12 "design C" closes all of them:
//  - block = 4 waves, 64 rows; lane = ROW: own x[32] in VGPRs (no X
//    broadcast anywhere), one coalesced load + one vmcnt wait per wave
//  - rules split across waves (wave w: rules 16w..16w+15) -> 6250 waves,
//    4/SIMD resident (LDS-capped 4 blocks/CU)
//  - q/pn table staged block-wide into LDS once; per rule 16 uniform
//    ds_read_b128 (broadcast, conflict-free); 16-rule loop FULLY UNROLLED
//    so the scheduler overlaps next-rule reads with current-rule math
//  - no cross-lane reduce: per-lane S over 16 rules; 4 partials via LDS
//  - mem tile [rule][row] pitch 68: conflict-free writes, 2-way reads,
//    fully-coalesced float4 global stores

typedef float v2f __attribute__((ext_vector_type(2)));

constexpr int DDIM   = 32;
constexpr int RR     = 64;
constexpr int ROWS   = 64;   // rows per block
constexpr int MP     = 68;   // mem tile pitch (floats)
constexpr int PP     = 5;    // partials pitch (floats)

__device__ inline float fast_exp2(float x) {
#if __has_builtin(__builtin_amdgcn_exp2f)
    return __builtin_amdgcn_exp2f(x);
#else
    return exp2f(x);
#endif
}

// ---- setup: per-rule table [ q[0..31] | pn[0..31] ] (64 floats/rule) ----
__global__ void gauss_setup_kernel(const float* __restrict__ centers,
                                   const float* __restrict__ sigma,
                                   float* __restrict__ ws) {
    const float SQK = 0.84932180028801907f;   // sqrt(0.5 * log2(e))
    int idx = blockIdx.x * blockDim.x + threadIdx.x;
    if (idx < RR * 64) {
        int r = idx >> 6, k = idx & 63, d = k & 31;
        float q = SQK / (sigma[r * DDIM + d] + 1e-8f);
        ws[idx] = (k < DDIM) ? q : (-centers[r * DDIM + d] * q);
    }
}

__global__ __launch_bounds__(256, 4) void gauss_main(
    const float* __restrict__ X,
    const float* __restrict__ tab,    // d_ws: 64 rules x [q[32]|pn[32]]
    float* __restrict__ out, int N)
{
    __shared__ float tabL[RR * 64];       // 16 KB
    __shared__ float memL[RR * MP];       // 17.0 KB  [rule][row]
    __shared__ float partL[ROWS * PP];    // 1.3 KB   [row][wave]

    const int tid  = threadIdx.x;
    const int lane = tid & 63;
    const int w    = tid >> 6;
    const int n0   = blockIdx.x * ROWS;

    // ---- stage constant table into LDS (1024 float4 by 256 threads) ----
    #pragma unroll
    for (int j = 0; j < 4; ++j) {
        reinterpret_cast<float4*>(tabL)[j * 256 + tid] =
            reinterpret_cast<const float4*>(tab)[j * 256 + tid];
    }

    // ---- own row -> VGPRs (per-lane coalesced; latency overlaps staging) ----
    const int n  = n0 + lane;
    const int nn = (n < N) ? n : (N - 1);   // clamp; stores predicated
    const float4* __restrict__ xr =
        reinterpret_cast<const float4*>(X + (size_t)nn * DDIM);
    v2f x2[16];
    #pragma unroll
    for (int j = 0; j < 8; ++j) {
        float4 v = xr[j];
        x2[2 * j]     = (v2f){v.x, v.y};
        x2[2 * j + 1] = (v2f){v.z, v.w};
    }
    #pragma unroll
    for (int j = 0; j < 16; ++j) asm volatile("" : "+v"(x2[j]));

    __syncthreads();   // table ready

    const float LC = -26.575424759098897f;   // log2(1e-8)
    const v2f L2 = {LC, LC};
    float S = 0.f;

    // ---- 16 rules for this wave, fully unrolled ----
    #pragma unroll
    for (int rr = 0; rr < 16; ++rr) {
        const int r = w * 16 + rr;
        const float4* __restrict__ tp =
            reinterpret_cast<const float4*>(&tabL[r * 64]);

        v2f acc[4] = {{0.f,0.f},{0.f,0.f},{0.f,0.f},{0.f,0.f}};
        #pragma unroll
        for (int j = 0; j < 8; ++j) {
            float4 qf = tp[j];        // q  dims 4j..4j+3 (uniform broadcast)
            float4 pf = tp[8 + j];    // pn dims 4j..4j+3
            v2f q0 = {qf.x, qf.y}, q1 = {qf.z, qf.w};
            v2f p0 = {pf.x, pf.y}, p1 = {pf.z, pf.w};
            v2f t0 = __builtin_elementwise_fma(q0, x2[2 * j],     p0);
            v2f t1 = __builtin_elementwise_fma(q1, x2[2 * j + 1], p1);
            // acc += max(-t^2, L)
            v2f u0 = __builtin_elementwise_fma(t0, -t0, acc[(2 * j) & 3]);
            v2f u1 = __builtin_elementwise_fma(t1, -t1, acc[(2 * j + 1) & 3]);
            v2f c0 = acc[(2 * j) & 3] + L2;
            v2f c1 = acc[(2 * j + 1) & 3] + L2;
            acc[(2 * j) & 3]     = __builtin_elementwise_max(u0, c0);
            acc[(2 * j + 1) & 3] = __builtin_elementwise_max(u1, c1);
        }
        v2f a = (acc[0] + acc[1]) + (acc[2] + acc[3]);
        float mem = fast_exp2(a.x + a.y);
        S += mem;
        memL[r * MP + lane] = mem;    // stride-1 across lanes: conflict-free
    }
    partL[lane * PP + w] = S;         // (5*lane+w)%32: 2-way, free

    __syncthreads();   // mem tile + partials ready

    // ---- epilogue: normalize + fully-coalesced float4 stores ----
    const int i  = tid >> 2;          // row 0..63
    const int qd = tid & 3;           // rule-quad selector
    float Ssum = partL[i * PP + 0] + partL[i * PP + 1] +
                 partL[i * PP + 2] + partL[i * PP + 3];
    float rs = __builtin_amdgcn_rcpf(Ssum + 1e-8f);
    if (n0 + i < N) {
        #pragma unroll
        for (int t = 0; t < 4; ++t) {
            const int r4 = t * 16 + qd * 4;
            float4 o;
            o.x = memL[(r4 + 0) * MP + i] * rs;
            o.y = memL[(r4 + 1) * MP + i] * rs;
            o.z = memL[(r4 + 2) * MP + i] * rs;
            o.w = memL[(r4 + 3) * MP + i] * rs;
            *reinterpret_cast<float4*>(&out[(size_t)(n0 + i) * RR + r4]) = o;
        }
    }
}

extern "C" void kernel_launch(void* const* d_in, const int* in_sizes, int n_in,
                              void* d_out, int out_size, void* d_ws, size_t ws_size,
                              hipStream_t stream) {
    const float* X       = (const float*)d_in[0];
    const float* centers = (const float*)d_in[1];
    const float* sigma   = (const float*)d_in[2];
    float* out = (float*)d_out;
    float* ws  = (float*)d_ws;   // needs 64*64*4 = 16 KB

    const int N = in_sizes[0] / DDIM;  // 100000

    // 1) build per-rule q/pn table (4096 floats)
    gauss_setup_kernel<<<16, 256, 0, stream>>>(centers, sigma, ws);

    // 2) main: 1563 blocks x 256 threads (64 rows/block, rules split 4 ways)
    const int grid = (N + ROWS - 1) / ROWS;
    gauss_main<<<grid, 256, 0, stream>>>(X, ws, out, N);
}